// Round 17
// baseline (128.254 us; speedup 1.0000x reference)
//
#include <hip/hip_runtime.h>

#define TEMP 5.656854249492380195f   // sqrt(32)
#define EPSG 1e-10f

// K1 GEMM geometry: M-tile 64 (8 b x 8 v), N 64 (q|k), K chunk 64, 8 chunks.
#define XSTR 68                      // x-tile row stride (floats)
#define WSTR 64                      // w-tile row stride

// ---------- K1: canonical LDS GEMM for q/k projection + argmax + hmean -----
// FROZEN round-11 version (50us; LDS-read-throughput-bound ~41us floor).
__launch_bounds__(256, 2)
__global__ void k1_kernel(const float* __restrict__ hidden,
                          const float* __restrict__ u_var,
                          const float* __restrict__ Wq,
                          const float* __restrict__ bq,
                          const float* __restrict__ Wk,
                          const float* __restrict__ bk,
                          const float* __restrict__ rule_emb,
                          const float* __restrict__ Wk2,
                          const float* __restrict__ bk2,
                          float* __restrict__ k2f,
                          int* __restrict__ selbuf,
                          float* __restrict__ outbuf) {
    const int tid = threadIdx.x;
    const int b0  = blockIdx.x * 8;

    __shared__ float4 smem4[(64 * XSTR + 64 * WSTR) / 4];
    float* smem = reinterpret_cast<float*>(smem4);
    float* xt = smem;
    float* wt = smem + 64 * XSTR;

    // merged K0 (block 0 only): k2 = rule_emb@Wk2 + bk2
    if (blockIdx.x == 0) {
        for (int t = tid; t < 512; t += 256) {
            int r = t >> 5, d = t & 31;
            float acc = bk2[d];
            for (int h = 0; h < 64; ++h)
                acc += rule_emb[r * 64 + h] * Wk2[h * 32 + d];
            k2f[t] = acc;
        }
    }

    const int tn = tid & 15;
    const int tm = tid >> 4;

    float4 acc0 = make_float4(0.f, 0.f, 0.f, 0.f);
    float4 acc1 = make_float4(0.f, 0.f, 0.f, 0.f);
    float4 acc2 = make_float4(0.f, 0.f, 0.f, 0.f);
    float4 acc3 = make_float4(0.f, 0.f, 0.f, 0.f);

    for (int c = 0; c < 8; ++c) {
        #pragma unroll
        for (int p = 0; p < 4; ++p) {
            int f   = p * 256 + tid;
            int row = f >> 4;
            int c4  = f & 15;
            int bb  = row >> 3, v = row & 7;
            float4 val = *reinterpret_cast<const float4*>(
                hidden + (size_t)(b0 + bb) * 4096 + v * 512 + c * 64 + c4 * 4);
            *reinterpret_cast<float4*>(&xt[row * XSTR + c4 * 4]) = val;
        }
        #pragma unroll
        for (int p = 0; p < 4; ++p) {
            int f  = p * 256 + tid;
            int k  = f >> 4;
            int n4 = f & 15;
            int h  = c * 64 + k;
            const float* src = (n4 < 8) ? (Wq + h * 32 + n4 * 4)
                                        : (Wk + h * 32 + (n4 - 8) * 4);
            *reinterpret_cast<float4*>(&wt[k * WSTR + n4 * 4]) =
                *reinterpret_cast<const float4*>(src);
        }
        __syncthreads();

        #pragma unroll 4
        for (int k4 = 0; k4 < 16; ++k4) {
            float4 x0 = *reinterpret_cast<const float4*>(&xt[(tm * 4 + 0) * XSTR + k4 * 4]);
            float4 x1 = *reinterpret_cast<const float4*>(&xt[(tm * 4 + 1) * XSTR + k4 * 4]);
            float4 x2 = *reinterpret_cast<const float4*>(&xt[(tm * 4 + 2) * XSTR + k4 * 4]);
            float4 x3 = *reinterpret_cast<const float4*>(&xt[(tm * 4 + 3) * XSTR + k4 * 4]);
            float4 w0 = *reinterpret_cast<const float4*>(&wt[(k4 * 4 + 0) * WSTR + tn * 4]);
            float4 w1 = *reinterpret_cast<const float4*>(&wt[(k4 * 4 + 1) * WSTR + tn * 4]);
            float4 w2 = *reinterpret_cast<const float4*>(&wt[(k4 * 4 + 2) * WSTR + tn * 4]);
            float4 w3 = *reinterpret_cast<const float4*>(&wt[(k4 * 4 + 3) * WSTR + tn * 4]);
            acc0.x += x0.x * w0.x + x0.y * w1.x + x0.z * w2.x + x0.w * w3.x;
            acc0.y += x0.x * w0.y + x0.y * w1.y + x0.z * w2.y + x0.w * w3.y;
            acc0.z += x0.x * w0.z + x0.y * w1.z + x0.z * w2.z + x0.w * w3.z;
            acc0.w += x0.x * w0.w + x0.y * w1.w + x0.z * w2.w + x0.w * w3.w;
            acc1.x += x1.x * w0.x + x1.y * w1.x + x1.z * w2.x + x1.w * w3.x;
            acc1.y += x1.x * w0.y + x1.y * w1.y + x1.z * w2.y + x1.w * w3.y;
            acc1.z += x1.x * w0.z + x1.y * w1.z + x1.z * w2.z + x1.w * w3.z;
            acc1.w += x1.x * w0.w + x1.y * w1.w + x1.z * w2.w + x1.w * w3.w;
            acc2.x += x2.x * w0.x + x2.y * w1.x + x2.z * w2.x + x2.w * w3.x;
            acc2.y += x2.x * w0.y + x2.y * w1.y + x2.z * w2.y + x2.w * w3.y;
            acc2.z += x2.x * w0.z + x2.y * w1.z + x2.z * w2.z + x2.w * w3.z;
            acc2.w += x2.x * w0.w + x2.y * w1.w + x2.z * w2.w + x2.w * w3.w;
            acc3.x += x3.x * w0.x + x3.y * w1.x + x3.z * w2.x + x3.w * w3.x;
            acc3.y += x3.x * w0.y + x3.y * w1.y + x3.z * w2.y + x3.w * w3.y;
            acc3.z += x3.x * w0.z + x3.y * w1.z + x3.z * w2.z + x3.w * w3.z;
            acc3.w += x3.x * w0.w + x3.y * w1.w + x3.z * w2.w + x3.w * w3.w;
        }

        {
            int bb = tid >> 5, hg = tid & 31;
            float m0 = 0.f, m1 = 0.f;
            #pragma unroll
            for (int v = 0; v < 8; ++v) {
                float2 x2 = *reinterpret_cast<const float2*>(&xt[(bb * 8 + v) * XSTR + hg * 2]);
                m0 += x2.x; m1 += x2.y;
            }
            float2 o; o.x = m0 * 0.125f; o.y = m1 * 0.125f;
            *reinterpret_cast<float2*>(outbuf + (size_t)(b0 + bb) * 4096 + c * 64 + hg * 2) = o;
        }
        __syncthreads();
    }

    {
        const float* bsrc = (tn < 8) ? (bq + tn * 4) : (bk + (tn - 8) * 4);
        float4 bias4 = *reinterpret_cast<const float4*>(bsrc);
        float4 r0, r1, r2, r3;
        r0.x = acc0.x + bias4.x; r0.y = acc0.y + bias4.y; r0.z = acc0.z + bias4.z; r0.w = acc0.w + bias4.w;
        r1.x = acc1.x + bias4.x; r1.y = acc1.y + bias4.y; r1.z = acc1.z + bias4.z; r1.w = acc1.w + bias4.w;
        r2.x = acc2.x + bias4.x; r2.y = acc2.y + bias4.y; r2.z = acc2.z + bias4.z; r2.w = acc2.w + bias4.w;
        r3.x = acc3.x + bias4.x; r3.y = acc3.y + bias4.y; r3.z = acc3.z + bias4.z; r3.w = acc3.w + bias4.w;
        float* sq = smem;
        *reinterpret_cast<float4*>(&sq[(tm * 4 + 0) * XSTR + tn * 4]) = r0;
        *reinterpret_cast<float4*>(&sq[(tm * 4 + 1) * XSTR + tn * 4]) = r1;
        *reinterpret_cast<float4*>(&sq[(tm * 4 + 2) * XSTR + tn * 4]) = r2;
        *reinterpret_cast<float4*>(&sq[(tm * 4 + 3) * XSTR + tn * 4]) = r3;
    }
    __syncthreads();

    {
        const float* sq = smem;
        const int w    = tid >> 6;
        const int lane = tid & 63;
        #pragma unroll
        for (int half = 0; half < 2; ++half) {
            const int bb = w + half * 4;
            const int b  = b0 + bb;
            const int i = lane >> 3, j = lane & 7;
            float s = 0.f;
            #pragma unroll
            for (int d4 = 0; d4 < 8; ++d4) {
                float4 qv = *reinterpret_cast<const float4*>(&sq[(bb * 8 + i) * XSTR + d4 * 4]);
                float4 kv = *reinterpret_cast<const float4*>(&sq[(bb * 8 + j) * XSTR + 32 + d4 * 4]);
                s += qv.x * kv.x + qv.y * kv.y + qv.z * kv.z + qv.w * kv.w;
            }
            s /= TEMP;
            float u = u_var[(size_t)b * 64 + lane];
            float g = -logf(-logf(u + EPSG) + EPSG);
            float pm = s + g;
            int idx = lane;
            #pragma unroll
            for (int off = 32; off >= 1; off >>= 1) {
                float pv = __shfl_xor(pm, off);
                int   pi = __shfl_xor(idx, off);
                if (pv > pm || (pv == pm && pi < idx)) { pm = pv; idx = pi; }
            }
            if (lane == 0) selbuf[b] = idx;
        }
    }
}

// ---------- K23: fused q2 GEMM + rule argmax + block-per-b MLP + write -----
// 4 b's/block, grid 1024. Staging + q2 + rule-argmax identical to the
// verified round-16 k23. MLP tail replaced with the R14-proven block-per-b
// pattern looped over bb (3 barriers/bb); comb already in LDS.
__launch_bounds__(256, 3)
__global__ void k23_kernel(const float* __restrict__ hidden,
                           const float* __restrict__ u_rule,
                           const float* __restrict__ Wq2,
                           const float* __restrict__ bq2,
                           const float* __restrict__ k2f,
                           const int* __restrict__ selbuf,
                           const float* __restrict__ hmeanbuf,
                           const float* __restrict__ W1,
                           const float* __restrict__ W2,
                           float* __restrict__ outbuf) {
    const int tid = threadIdx.x;
    const int b0  = blockIdx.x * 4;

    __shared__ float  s_k2[512];
    __shared__ float  comb[4][1024];    // [bb][h_p | h_c] (16 KB)
    __shared__ float  hm[4][512];       // hmean (8 KB)
    __shared__ float4 part4[4][4][8];
    __shared__ float  s_q2[4][32];
    __shared__ int    s_sel4[4];
    __shared__ int    s_rsel[4];
    __shared__ float  part[4][16];
    __shared__ float  s_h1[16];
    __shared__ float  s_rout[512];

    s_k2[tid]       = k2f[tid];
    s_k2[tid + 256] = k2f[tid + 256];
    if (tid < 4) s_sel4[tid] = selbuf[b0 + tid];
    __syncthreads();

    // ---- stage comb (js|cs rows) + hmean for 4 b's ----
    {
        const float4* h4 = reinterpret_cast<const float4*>(hidden);
        #pragma unroll
        for (int p = 0; p < 4; ++p) {
            int f   = p * 256 + tid;        // float4 idx, 1024 total
            int bb  = f >> 8, idx = f & 255;
            int half = idx >> 7, c = idx & 127;
            int sv  = s_sel4[bb];
            int row = half ? (sv >> 3) : (sv & 7);
            float4 v = h4[((size_t)(b0 + bb) * 8 + row) * 128 + c];
            *reinterpret_cast<float4*>(&comb[bb][idx * 4]) = v;
        }
        #pragma unroll
        for (int p = 0; p < 2; ++p) {
            int f  = p * 256 + tid;         // 512 float4 total
            int bb = f >> 7, c = f & 127;
            float4 v = *reinterpret_cast<const float4*>(
                hmeanbuf + (size_t)(b0 + bb) * 4096 + c * 4);
            *reinterpret_cast<float4*>(&hm[bb][c * 4]) = v;
        }
    }
    __syncthreads();

    // ---- q2 GEMM (FP order identical to verified round-16 k23) ----
    {
        const int d4 = tid & 7, s = tid >> 3;
        float4 acc[4];
        #pragma unroll
        for (int bb = 0; bb < 4; ++bb) acc[bb] = make_float4(0.f, 0.f, 0.f, 0.f);

        for (int kt = 0; kt < 6; ++kt) {
            float4 w[8];
            #pragma unroll
            for (int j = 0; j < 8; ++j)
                w[j] = *reinterpret_cast<const float4*>(
                    Wq2 + (size_t)(kt * 256 + s * 8 + j) * 32 + d4 * 4);
            #pragma unroll
            for (int bb = 0; bb < 4; ++bb) {
                const float* xsrc = (kt < 4) ? &comb[bb][kt * 256]
                                             : &hm[bb][(kt - 4) * 256];
                #pragma unroll
                for (int j = 0; j < 8; ++j) {
                    float x = xsrc[s * 8 + j];
                    acc[bb].x += x * w[j].x;
                    acc[bb].y += x * w[j].y;
                    acc[bb].z += x * w[j].z;
                    acc[bb].w += x * w[j].w;
                }
            }
        }
        #pragma unroll
        for (int off = 8; off < 64; off <<= 1) {
            #pragma unroll
            for (int bb = 0; bb < 4; ++bb) {
                acc[bb].x += __shfl_xor(acc[bb].x, off);
                acc[bb].y += __shfl_xor(acc[bb].y, off);
                acc[bb].z += __shfl_xor(acc[bb].z, off);
                acc[bb].w += __shfl_xor(acc[bb].w, off);
            }
        }
        if ((s & 7) == 0) {
            #pragma unroll
            for (int bb = 0; bb < 4; ++bb) part4[tid >> 6][bb][d4] = acc[bb];
        }
    }
    __syncthreads();
    if (tid < 128) {
        const int bb = tid >> 5, col = tid & 31;
        float q2 = bq2[col];
        #pragma unroll
        for (int wv = 0; wv < 4; ++wv) {
            const float* pf = reinterpret_cast<const float*>(&part4[wv][bb][col >> 2]);
            q2 += pf[col & 3];
        }
        s_q2[bb][col] = q2;
    }
    __syncthreads();
    if (tid < 64) {
        const int bb = tid >> 4, r = tid & 15;
        const int b = b0 + bb;
        float sc = 0.f;
        #pragma unroll
        for (int d = 0; d < 32; ++d) sc += s_q2[bb][d] * s_k2[r * 32 + d];
        sc /= TEMP;
        float u = u_rule[(size_t)b * 16 + r];
        float g = -logf(-logf(u + EPSG) + EPSG);
        float pm = sc + g;
        int idx = r;
        #pragma unroll
        for (int off = 8; off >= 1; off >>= 1) {
            float pv = __shfl_xor(pm, off, 16);
            int   pi = __shfl_xor(idx, off, 16);
            if (pv > pm || (pv == pm && pi < idx)) { pm = pv; idx = pi; }
        }
        if (r == 0) s_rsel[bb] = idx;
    }
    __syncthreads();

    // ---- MLP + write: block-per-b (R14 pattern), looped over bb ----
    for (int bb = 0; bb < 4; ++bb) {
        const int b  = b0 + bb;
        const int sv = s_sel4[bb];
        const int r  = s_rsel[bb];
        const int js = sv & 7;

        // h1 partials: thread (e = tid&15, sl = tid>>4); W1 from L2
        {
            const int e  = tid & 15;
            const int sl = tid >> 4;
            const float* cb  = comb[bb];
            const float* w1p = W1 + (size_t)r * 16384;
            float a = 0.f;
            for (int i = 0; i < 64; ++i) {
                int rr = i * 16 + sl;
                a += cb[rr] * w1p[rr * 16 + e];
            }
            a += __shfl_xor(a, 16);
            a += __shfl_xor(a, 32);
            if ((sl & 3) == 0) part[sl >> 2][e] = a;
        }
        __syncthreads();
        if (tid < 16)
            s_h1[tid] = fmaxf(part[0][tid] + part[1][tid] + part[2][tid] + part[3][tid], 0.f);
        __syncthreads();

        // rout cols tid*2, tid*2+1
        {
            const float* w2 = W2 + (size_t)r * 8192;
            int o0 = tid * 2;
            float a0 = 0.f, a1 = 0.f;
            #pragma unroll
            for (int ee = 0; ee < 16; ++ee) {
                float h1e = s_h1[ee];
                float2 ww = *reinterpret_cast<const float2*>(w2 + ee * 512 + o0);
                a0 += h1e * ww.x;
                a1 += h1e * ww.y;
            }
            s_rout[o0]     = a0;
            s_rout[o0 + 1] = a1;
        }
        __syncthreads();

        // streaming write: thread t -> slot v = t>>5, 16 cols at (t&31)*16
        {
            const int v    = tid >> 5;
            const int col0 = (tid & 31) * 16;
            float4 z = make_float4(0.f, 0.f, 0.f, 0.f);
            float4 r0 = z, r1 = z, r2 = z, r3 = z;
            if (v == js) {
                r0 = *reinterpret_cast<const float4*>(&s_rout[col0]);
                r1 = *reinterpret_cast<const float4*>(&s_rout[col0 + 4]);
                r2 = *reinterpret_cast<const float4*>(&s_rout[col0 + 8]);
                r3 = *reinterpret_cast<const float4*>(&s_rout[col0 + 12]);
            }
            float* ob = outbuf + (size_t)b * 4096 + v * 512 + col0;
            *reinterpret_cast<float4*>(ob)      = r0;
            *reinterpret_cast<float4*>(ob + 4)  = r1;
            *reinterpret_cast<float4*>(ob + 8)  = r2;
            *reinterpret_cast<float4*>(ob + 12) = r3;
        }
        // no trailing barrier needed: next iter's s_rout writes are ordered
        // behind two barriers; part/s_h1 reuse likewise protected.
    }
}

extern "C" void kernel_launch(void* const* d_in, const int* in_sizes, int n_in,
                              void* d_out, int out_size, void* d_ws, size_t ws_size,
                              hipStream_t stream) {
    const float* hidden   = (const float*)d_in[0];
    const float* u_var    = (const float*)d_in[1];
    const float* u_rule   = (const float*)d_in[2];
    const float* Wq       = (const float*)d_in[3];
    const float* bq       = (const float*)d_in[4];
    const float* Wk       = (const float*)d_in[5];
    const float* bk       = (const float*)d_in[6];
    const float* rule_emb = (const float*)d_in[7];
    const float* Wq2      = (const float*)d_in[8];
    const float* bq2      = (const float*)d_in[9];
    const float* Wk2      = (const float*)d_in[10];
    const float* bk2      = (const float*)d_in[11];
    const float* W1       = (const float*)d_in[12];
    const float* W2       = (const float*)d_in[13];

    char* ws = (char*)d_ws;
    float* k2f  = (float*)(ws);              // 512 f32
    int*   sel  = (int*)(ws + 4096);         // 4096 i32
    float* outf = (float*)d_out;

    hipLaunchKernelGGL(k1_kernel, dim3(512), dim3(256), 0, stream,
                       hidden, u_var, Wq, bq, Wk, bk,
                       rule_emb, Wk2, bk2, k2f, sel, outf);
    hipLaunchKernelGGL(k23_kernel, dim3(1024), dim3(256), 0, stream,
                       hidden, u_rule, Wq2, bq2, k2f, sel, outf, W1, W2, outf);
}

// Round 18
// 90.395 us; speedup vs baseline: 1.4188x; 1.4188x over previous
//
#include <hip/hip_runtime.h>

#define TEMP 5.656854249492380195f   // sqrt(32)
#define EPSG 1e-10f

// K1 GEMM geometry: M-tile 64 (8 b x 8 v), N 64 (q|k), K chunk 64, 8 chunks.
#define XSTR 68                      // x-tile row stride (floats)
#define WSTR 64                      // w-tile row stride

// ---------- K1': proj GEMM + argmax (frozen R11 FP) + fused q2/rule tail ---
// GEMM/argmax sections byte-identical in FP order to the frozen 50us kernel.
// hmean goes to LDS (same adds). After argmax the xt/wt region is dead ->
// reused for comb[8][1024]; q2 GEMM + rule argmax copied verbatim from the
// verified R13/R16 code (zero inner barriers). No outbuf writes here.
__launch_bounds__(256, 2)
__global__ void k1_kernel(const float* __restrict__ hidden,
                          const float* __restrict__ u_var,
                          const float* __restrict__ u_rule,
                          const float* __restrict__ Wq,
                          const float* __restrict__ bq,
                          const float* __restrict__ Wk,
                          const float* __restrict__ bk,
                          const float* __restrict__ rule_emb,
                          const float* __restrict__ Wk2,
                          const float* __restrict__ bk2,
                          const float* __restrict__ Wq2,
                          const float* __restrict__ bq2,
                          int* __restrict__ selbuf,
                          int* __restrict__ rselbuf) {
    const int tid = threadIdx.x;
    const int b0  = blockIdx.x * 8;

    __shared__ float4 smem4[(64 * XSTR + 64 * WSTR) / 4];   // 33.8 KB
    float* smem = reinterpret_cast<float*>(smem4);
    float* xt = smem;
    float* wt = smem + 64 * XSTR;
    __shared__ float  hm[8 * 512];        // 16 KB hmean
    __shared__ float  sk2[512];           // 2 KB
    __shared__ float4 part4[4][8][8];     // 4 KB
    __shared__ float  s_q2[8][32];        // 1 KB
    __shared__ int    ssel[8];

    // per-block k2 = rule_emb @ Wk2 + bk2 (identical formula to before)
    for (int t = tid; t < 512; t += 256) {
        int r = t >> 5, d = t & 31;
        float acc = bk2[d];
        for (int h = 0; h < 64; ++h)
            acc += rule_emb[r * 64 + h] * Wk2[h * 32 + d];
        sk2[t] = acc;
    }

    const int tn = tid & 15;
    const int tm = tid >> 4;

    float4 acc0 = make_float4(0.f, 0.f, 0.f, 0.f);
    float4 acc1 = make_float4(0.f, 0.f, 0.f, 0.f);
    float4 acc2 = make_float4(0.f, 0.f, 0.f, 0.f);
    float4 acc3 = make_float4(0.f, 0.f, 0.f, 0.f);

    for (int c = 0; c < 8; ++c) {
        #pragma unroll
        for (int p = 0; p < 4; ++p) {
            int f   = p * 256 + tid;
            int row = f >> 4;
            int c4  = f & 15;
            int bb  = row >> 3, v = row & 7;
            float4 val = *reinterpret_cast<const float4*>(
                hidden + (size_t)(b0 + bb) * 4096 + v * 512 + c * 64 + c4 * 4);
            *reinterpret_cast<float4*>(&xt[row * XSTR + c4 * 4]) = val;
        }
        #pragma unroll
        for (int p = 0; p < 4; ++p) {
            int f  = p * 256 + tid;
            int k  = f >> 4;
            int n4 = f & 15;
            int h  = c * 64 + k;
            const float* src = (n4 < 8) ? (Wq + h * 32 + n4 * 4)
                                        : (Wk + h * 32 + (n4 - 8) * 4);
            *reinterpret_cast<float4*>(&wt[k * WSTR + n4 * 4]) =
                *reinterpret_cast<const float4*>(src);
        }
        __syncthreads();

        #pragma unroll 4
        for (int k4 = 0; k4 < 16; ++k4) {
            float4 x0 = *reinterpret_cast<const float4*>(&xt[(tm * 4 + 0) * XSTR + k4 * 4]);
            float4 x1 = *reinterpret_cast<const float4*>(&xt[(tm * 4 + 1) * XSTR + k4 * 4]);
            float4 x2 = *reinterpret_cast<const float4*>(&xt[(tm * 4 + 2) * XSTR + k4 * 4]);
            float4 x3 = *reinterpret_cast<const float4*>(&xt[(tm * 4 + 3) * XSTR + k4 * 4]);
            float4 w0 = *reinterpret_cast<const float4*>(&wt[(k4 * 4 + 0) * WSTR + tn * 4]);
            float4 w1 = *reinterpret_cast<const float4*>(&wt[(k4 * 4 + 1) * WSTR + tn * 4]);
            float4 w2 = *reinterpret_cast<const float4*>(&wt[(k4 * 4 + 2) * WSTR + tn * 4]);
            float4 w3 = *reinterpret_cast<const float4*>(&wt[(k4 * 4 + 3) * WSTR + tn * 4]);
            acc0.x += x0.x * w0.x + x0.y * w1.x + x0.z * w2.x + x0.w * w3.x;
            acc0.y += x0.x * w0.y + x0.y * w1.y + x0.z * w2.y + x0.w * w3.y;
            acc0.z += x0.x * w0.z + x0.y * w1.z + x0.z * w2.z + x0.w * w3.z;
            acc0.w += x0.x * w0.w + x0.y * w1.w + x0.z * w2.w + x0.w * w3.w;
            acc1.x += x1.x * w0.x + x1.y * w1.x + x1.z * w2.x + x1.w * w3.x;
            acc1.y += x1.x * w0.y + x1.y * w1.y + x1.z * w2.y + x1.w * w3.y;
            acc1.z += x1.x * w0.z + x1.y * w1.z + x1.z * w2.z + x1.w * w3.z;
            acc1.w += x1.x * w0.w + x1.y * w1.w + x1.z * w2.w + x1.w * w3.w;
            acc2.x += x2.x * w0.x + x2.y * w1.x + x2.z * w2.x + x2.w * w3.x;
            acc2.y += x2.x * w0.y + x2.y * w1.y + x2.z * w2.y + x2.w * w3.y;
            acc2.z += x2.x * w0.z + x2.y * w1.z + x2.z * w2.z + x2.w * w3.z;
            acc2.w += x2.x * w0.w + x2.y * w1.w + x2.z * w2.w + x2.w * w3.w;
            acc3.x += x3.x * w0.x + x3.y * w1.x + x3.z * w2.x + x3.w * w3.x;
            acc3.y += x3.x * w0.y + x3.y * w1.y + x3.z * w2.y + x3.w * w3.y;
            acc3.z += x3.x * w0.z + x3.y * w1.z + x3.z * w2.z + x3.w * w3.z;
            acc3.w += x3.x * w0.w + x3.y * w1.w + x3.z * w2.w + x3.w * w3.w;
        }

        // hmean partial -> LDS (same adds/order as frozen kernel)
        {
            int bb = tid >> 5, hg = tid & 31;
            float m0 = 0.f, m1 = 0.f;
            #pragma unroll
            for (int v = 0; v < 8; ++v) {
                float2 x2 = *reinterpret_cast<const float2*>(&xt[(bb * 8 + v) * XSTR + hg * 2]);
                m0 += x2.x; m1 += x2.y;
            }
            hm[bb * 512 + c * 64 + hg * 2]     = m0 * 0.125f;
            hm[bb * 512 + c * 64 + hg * 2 + 1] = m1 * 0.125f;
        }
        __syncthreads();
    }

    {
        const float* bsrc = (tn < 8) ? (bq + tn * 4) : (bk + (tn - 8) * 4);
        float4 bias4 = *reinterpret_cast<const float4*>(bsrc);
        float4 r0, r1, r2, r3;
        r0.x = acc0.x + bias4.x; r0.y = acc0.y + bias4.y; r0.z = acc0.z + bias4.z; r0.w = acc0.w + bias4.w;
        r1.x = acc1.x + bias4.x; r1.y = acc1.y + bias4.y; r1.z = acc1.z + bias4.z; r1.w = acc1.w + bias4.w;
        r2.x = acc2.x + bias4.x; r2.y = acc2.y + bias4.y; r2.z = acc2.z + bias4.z; r2.w = acc2.w + bias4.w;
        r3.x = acc3.x + bias4.x; r3.y = acc3.y + bias4.y; r3.z = acc3.z + bias4.z; r3.w = acc3.w + bias4.w;
        float* sq = smem;
        *reinterpret_cast<float4*>(&sq[(tm * 4 + 0) * XSTR + tn * 4]) = r0;
        *reinterpret_cast<float4*>(&sq[(tm * 4 + 1) * XSTR + tn * 4]) = r1;
        *reinterpret_cast<float4*>(&sq[(tm * 4 + 2) * XSTR + tn * 4]) = r2;
        *reinterpret_cast<float4*>(&sq[(tm * 4 + 3) * XSTR + tn * 4]) = r3;
    }
    __syncthreads();

    {
        const float* sq = smem;
        const int w    = tid >> 6;
        const int lane = tid & 63;
        #pragma unroll
        for (int half = 0; half < 2; ++half) {
            const int bb = w + half * 4;
            const int b  = b0 + bb;
            const int i = lane >> 3, j = lane & 7;
            float s = 0.f;
            #pragma unroll
            for (int d4 = 0; d4 < 8; ++d4) {
                float4 qv = *reinterpret_cast<const float4*>(&sq[(bb * 8 + i) * XSTR + d4 * 4]);
                float4 kv = *reinterpret_cast<const float4*>(&sq[(bb * 8 + j) * XSTR + 32 + d4 * 4]);
                s += qv.x * kv.x + qv.y * kv.y + qv.z * kv.z + qv.w * kv.w;
            }
            s /= TEMP;
            float u = u_var[(size_t)b * 64 + lane];
            float g = -logf(-logf(u + EPSG) + EPSG);
            float pm = s + g;
            int idx = lane;
            #pragma unroll
            for (int off = 32; off >= 1; off >>= 1) {
                float pv = __shfl_xor(pm, off);
                int   pi = __shfl_xor(idx, off);
                if (pv > pm || (pv == pm && pi < idx)) { pm = pv; idx = pi; }
            }
            if (lane == 0) { selbuf[b] = idx; ssel[bb] = idx; }
        }
    }
    __syncthreads();   // scores consumed; ssel visible

    // ---- stage comb[8][1024] into the dead xt/wt region (32 KB <= 33.8) ---
    {
        float* comb = smem;
        const float4* h4 = reinterpret_cast<const float4*>(hidden);
        #pragma unroll
        for (int p = 0; p < 8; ++p) {
            int f    = p * 256 + tid;      // 2048 float4 total
            int bb   = f >> 8, idx = f & 255;
            int half = idx >> 7, cc = idx & 127;
            int sv   = ssel[bb];
            int row  = half ? (sv >> 3) : (sv & 7);
            reinterpret_cast<float4*>(comb)[bb * 256 + idx] =
                h4[((size_t)(b0 + bb) * 8 + row) * 128 + cc];
        }
    }
    __syncthreads();

    // ---- q2 GEMM (verbatim R13/R16 FP order) + rule argmax ----
    {
        const float* comb = smem;
        const int d4 = tid & 7, s = tid >> 3;
        float4 acc[8];
        #pragma unroll
        for (int bb = 0; bb < 8; ++bb) acc[bb] = make_float4(0.f, 0.f, 0.f, 0.f);

        for (int kt = 0; kt < 6; ++kt) {
            float4 w[8];
            #pragma unroll
            for (int j = 0; j < 8; ++j)
                w[j] = *reinterpret_cast<const float4*>(
                    Wq2 + (size_t)(kt * 256 + s * 8 + j) * 32 + d4 * 4);
            #pragma unroll
            for (int bb = 0; bb < 8; ++bb) {
                const float* xsrc = (kt < 4) ? &comb[bb * 1024 + kt * 256]
                                             : &hm[bb * 512 + (kt - 4) * 256];
                #pragma unroll
                for (int j = 0; j < 8; ++j) {
                    float x = xsrc[s * 8 + j];
                    acc[bb].x += x * w[j].x;
                    acc[bb].y += x * w[j].y;
                    acc[bb].z += x * w[j].z;
                    acc[bb].w += x * w[j].w;
                }
            }
        }
        #pragma unroll
        for (int off = 8; off < 64; off <<= 1) {
            #pragma unroll
            for (int bb = 0; bb < 8; ++bb) {
                acc[bb].x += __shfl_xor(acc[bb].x, off);
                acc[bb].y += __shfl_xor(acc[bb].y, off);
                acc[bb].z += __shfl_xor(acc[bb].z, off);
                acc[bb].w += __shfl_xor(acc[bb].w, off);
            }
        }
        if ((s & 7) == 0) {
            #pragma unroll
            for (int bb = 0; bb < 8; ++bb) part4[tid >> 6][bb][d4] = acc[bb];
        }
    }
    __syncthreads();
    {
        const int bb = tid >> 5, col = tid & 31;
        float q2 = bq2[col];
        #pragma unroll
        for (int wv = 0; wv < 4; ++wv) {
            const float* pf = reinterpret_cast<const float*>(&part4[wv][bb][col >> 2]);
            q2 += pf[col & 3];
        }
        s_q2[bb][col] = q2;
    }
    __syncthreads();
    if (tid < 128) {
        const int bb = tid >> 4, r = tid & 15;
        const int b = b0 + bb;
        float sc = 0.f;
        #pragma unroll
        for (int d = 0; d < 32; ++d) sc += s_q2[bb][d] * sk2[r * 32 + d];
        sc /= TEMP;
        float u = u_rule[(size_t)b * 16 + r];
        float g = -logf(-logf(u + EPSG) + EPSG);
        float pm = sc + g;
        int idx = r;
        #pragma unroll
        for (int off = 8; off >= 1; off >>= 1) {
            float pv = __shfl_xor(pm, off, 16);
            int   pi = __shfl_xor(idx, off, 16);
            if (pv > pm || (pv == pm && pi < idx)) { pm = pv; idx = pi; }
        }
        if (r == 0) rselbuf[b] = idx;
    }
}

// ---------- K3: block-per-b MLP + coalesced streaming write (frozen R14) ---
__launch_bounds__(256, 4)
__global__ void k3_kernel(const float* __restrict__ hidden,
                          const float* __restrict__ W1,
                          const float* __restrict__ W2,
                          const int* __restrict__ selbuf,
                          const int* __restrict__ rselbuf,
                          float* __restrict__ outbuf) {
    const int tid = threadIdx.x;
    const int b   = blockIdx.x;

    __shared__ float comb[1024];
    __shared__ float part[4][16];
    __shared__ float s_h1[16];
    __shared__ float s_rout[512];

    const int sv = selbuf[b];
    const int r  = rselbuf[b];
    const int js = sv & 7, cs = sv >> 3;

    {
        const float4* h4 = reinterpret_cast<const float4*>(hidden);
        float4 v;
        if (tid < 128) v = h4[((size_t)b * 8 + js) * 128 + tid];
        else           v = h4[((size_t)b * 8 + cs) * 128 + (tid - 128)];
        *reinterpret_cast<float4*>(&comb[tid * 4]) = v;
    }
    __syncthreads();

    {
        const int e  = tid & 15;
        const int sl = tid >> 4;
        const float* w1p = W1 + (size_t)r * 16384;
        float a = 0.f;
        for (int i = 0; i < 64; ++i) {
            int rr = i * 16 + sl;
            a += comb[rr] * w1p[rr * 16 + e];
        }
        a += __shfl_xor(a, 16);
        a += __shfl_xor(a, 32);
        if ((sl & 3) == 0) part[sl >> 2][e] = a;
    }
    __syncthreads();
    if (tid < 16)
        s_h1[tid] = fmaxf(part[0][tid] + part[1][tid] + part[2][tid] + part[3][tid], 0.f);
    __syncthreads();

    {
        const float* w2 = W2 + (size_t)r * 8192;
        int o0 = tid * 2;
        float a0 = 0.f, a1 = 0.f;
        #pragma unroll
        for (int ee = 0; ee < 16; ++ee) {
            float h1e = s_h1[ee];
            float2 ww = *reinterpret_cast<const float2*>(w2 + ee * 512 + o0);
            a0 += h1e * ww.x;
            a1 += h1e * ww.y;
        }
        s_rout[o0]     = a0;
        s_rout[o0 + 1] = a1;
    }
    __syncthreads();

    {
        const int v    = tid >> 5;
        const int col0 = (tid & 31) * 16;
        float4 z = make_float4(0.f, 0.f, 0.f, 0.f);
        float4 r0 = z, r1 = z, r2 = z, r3 = z;
        if (v == js) {
            r0 = *reinterpret_cast<const float4*>(&s_rout[col0]);
            r1 = *reinterpret_cast<const float4*>(&s_rout[col0 + 4]);
            r2 = *reinterpret_cast<const float4*>(&s_rout[col0 + 8]);
            r3 = *reinterpret_cast<const float4*>(&s_rout[col0 + 12]);
        }
        float* ob = outbuf + (size_t)b * 4096 + v * 512 + col0;
        *reinterpret_cast<float4*>(ob)      = r0;
        *reinterpret_cast<float4*>(ob + 4)  = r1;
        *reinterpret_cast<float4*>(ob + 8)  = r2;
        *reinterpret_cast<float4*>(ob + 12) = r3;
    }
}

extern "C" void kernel_launch(void* const* d_in, const int* in_sizes, int n_in,
                              void* d_out, int out_size, void* d_ws, size_t ws_size,
                              hipStream_t stream) {
    const float* hidden   = (const float*)d_in[0];
    const float* u_var    = (const float*)d_in[1];
    const float* u_rule   = (const float*)d_in[2];
    const float* Wq       = (const float*)d_in[3];
    const float* bq       = (const float*)d_in[4];
    const float* Wk       = (const float*)d_in[5];
    const float* bk       = (const float*)d_in[6];
    const float* rule_emb = (const float*)d_in[7];
    const float* Wq2      = (const float*)d_in[8];
    const float* bq2      = (const float*)d_in[9];
    const float* Wk2      = (const float*)d_in[10];
    const float* bk2      = (const float*)d_in[11];
    const float* W1       = (const float*)d_in[12];
    const float* W2       = (const float*)d_in[13];

    char* ws = (char*)d_ws;
    int*   sel  = (int*)(ws + 4096);         // 4096 i32
    int*   rsel = (int*)(ws + 20480);        // 4096 i32
    float* outf = (float*)d_out;

    hipLaunchKernelGGL(k1_kernel, dim3(512), dim3(256), 0, stream,
                       hidden, u_var, u_rule, Wq, bq, Wk, bk,
                       rule_emb, Wk2, bk2, Wq2, bq2, sel, rsel);
    hipLaunchKernelGGL(k3_kernel, dim3(4096), dim3(256), 0, stream,
                       hidden, W1, W2, sel, rsel, outf);
}